// Round 4
// baseline (466.402 us; speedup 1.0000x reference)
//
#include <hip/hip_runtime.h>

typedef __attribute__((ext_vector_type(4))) float f32x4;
typedef __attribute__((ext_vector_type(8))) _Float16 half8;
typedef __attribute__((ext_vector_type(4))) _Float16 half4;

__device__ __forceinline__ float fast_tanh(float x) {
  float e = __expf(2.f * x);
  return 1.f - 2.f / (e + 1.f);
}
__device__ __forceinline__ float fast_sigmoid(float x) {
  return 1.f / (1.f + __expf(-x));
}

__device__ __forceinline__ void gl_lds16(const _Float16* g, _Float16* l) {
  __builtin_amdgcn_global_load_lds(
      (const __attribute__((address_space(1))) void*)g,
      (__attribute__((address_space(3))) void*)l, 16, 0, 0);
}

// ---------------------------------------------------------------------------
// gemm_big: C[512, 4096] = A[512,K] @ B[4096,K]^T. TM=512 (whole M: B read
// once from HBM), TN=64, 8 waves (wave w owns rows [w*64,w*64+64)), BK=32,
// double-buffered LDS (2-phase: stage-next || compute), XOR granule swizzle
// (both sides) for conflict-free ds_read_b128.
// grid = dim3(z, 64): blocks sharing z (A K-slice) stride 4 -> 2 XCDs share
// each A slab via L2. blockIdx.x = z (K-split), writes C + z*czstride.
// ---------------------------------------------------------------------------
template<int SPLIT, int OUT16>
__global__ __launch_bounds__(512, 2) void gemm_big(
    const _Float16* __restrict__ Ahp, const _Float16* __restrict__ Alp,
    const _Float16* __restrict__ Bhp, const _Float16* __restrict__ Blp,
    int K, int Kc, void* __restrict__ Cp, long czstride)
{
  __shared__ _Float16 sAh[2][512 * 32];
  __shared__ _Float16 sBh[2][64 * 32];
  __shared__ _Float16 sAl[SPLIT == 3 ? 2 : 1][SPLIT == 3 ? 512 * 32 : 8];
  __shared__ _Float16 sBl[SPLIT == 3 ? 2 : 1][SPLIT == 3 ? 64 * 32 : 8];

  const int lane = threadIdx.x & 63, wid = threadIdx.x >> 6;
  const int sr = lane >> 2;                               // staging row-in-16
  const int sgr = (lane & 3) ^ ((lane >> 3) & 3);         // swizzled src granule
  const int l16 = lane & 15, k8 = lane >> 4;
  const int koff = ((k8 ^ ((lane >> 1) & 3))) * 8;        // swizzled read offset

  const int  z     = blockIdx.x;
  const long nbase = (long)blockIdx.y * 64;
  const int  kt0   = z * Kc;

  f32x4 acc[4][4];
#pragma unroll
  for (int i = 0; i < 4; i++)
#pragma unroll
    for (int j = 0; j < 4; j++) acc[i][j] = (f32x4){0.f, 0.f, 0.f, 0.f};

  auto STAGE = [&](int buf, int kt) {
#pragma unroll
    for (int g = 0; g < 4; g++) {
      const int rloc = wid * 64 + g * 16 + sr;
      gl_lds16(Ahp + (long)rloc * K + kt + sgr * 8, &sAh[buf][(wid * 64 + g * 16) * 32]);
      if (SPLIT == 3)
        gl_lds16(Alp + (long)rloc * K + kt + sgr * 8, &sAl[buf][(wid * 64 + g * 16) * 32]);
    }
    if (wid < 4) {
      const int rloc = wid * 16 + sr;
      gl_lds16(Bhp + (nbase + rloc) * K + kt + sgr * 8, &sBh[buf][(wid * 16) * 32]);
    } else if (SPLIT == 3) {
      const int rloc = (wid - 4) * 16 + sr;
      gl_lds16(Blp + (nbase + rloc) * K + kt + sgr * 8, &sBl[buf][((wid - 4) * 16) * 32]);
    }
  };

  STAGE(0, kt0);
  __syncthreads();

  int buf = 0;
  const int nst = Kc >> 5;
  for (int t = 0; t < nst; t++) {
    if (t + 1 < nst) STAGE(buf ^ 1, kt0 + (t + 1) * 32);

    half8 ah[4], bh[4];
#pragma unroll
    for (int m = 0; m < 4; m++)
      ah[m] = *(const half8*)&sAh[buf][(wid * 64 + m * 16 + l16) * 32 + koff];
#pragma unroll
    for (int n = 0; n < 4; n++)
      bh[n] = *(const half8*)&sBh[buf][(n * 16 + l16) * 32 + koff];
#pragma unroll
    for (int m = 0; m < 4; m++)
#pragma unroll
      for (int n = 0; n < 4; n++)
        acc[m][n] = __builtin_amdgcn_mfma_f32_16x16x32_f16(ah[m], bh[n], acc[m][n], 0, 0, 0);
    if (SPLIT == 3) {
      half8 al[4], bl[4];
#pragma unroll
      for (int m = 0; m < 4; m++)
        al[m] = *(const half8*)&sAl[buf][(wid * 64 + m * 16 + l16) * 32 + koff];
#pragma unroll
      for (int n = 0; n < 4; n++)
        bl[n] = *(const half8*)&sBl[buf][(n * 16 + l16) * 32 + koff];
#pragma unroll
      for (int m = 0; m < 4; m++)
#pragma unroll
        for (int n = 0; n < 4; n++) {
          acc[m][n] = __builtin_amdgcn_mfma_f32_16x16x32_f16(al[m], bh[n], acc[m][n], 0, 0, 0);
          acc[m][n] = __builtin_amdgcn_mfma_f32_16x16x32_f16(ah[m], bl[n], acc[m][n], 0, 0, 0);
        }
    }
    __syncthreads();
    buf ^= 1;
  }

  const long czoff = (long)z * czstride;
#pragma unroll
  for (int m = 0; m < 4; m++)
#pragma unroll
    for (int n = 0; n < 4; n++) {
      const long row0 = wid * 64 + m * 16 + (lane >> 4) * 4;
      const long col  = nbase + n * 16 + l16;
#pragma unroll
      for (int j = 0; j < 4; j++) {
        const long idx = czoff + (row0 + j) * 4096 + col;
        if (OUT16) ((_Float16*)Cp)[idx] = (_Float16)acc[m][n][j];
        else       ((float*)Cp)[idx] = acc[m][n][j];
      }
    }
}

// ---------------------------------------------------------------------------
// 128x128 tile GEMM (4 waves) for the smaller matmuls; single-buffer 2-barrier
// structure + XOR granule swizzle. SWAPXY=1: blockIdx.x=M-tile, y=N-tile
// (same-M blocks stride gridDim.x -> same XCD when gridDim.x % 8 == 0).
// ---------------------------------------------------------------------------
template<int SPLIT, int OUT16, int NGUARD, int SWAPXY>
__global__ __launch_bounds__(256) void gemm16(
    const _Float16* __restrict__ Ahp, const _Float16* __restrict__ Alp, int lda,
    const _Float16* __restrict__ Bhp, const _Float16* __restrict__ Blp, int ldb,
    void* __restrict__ Cp, int ldc, long czstride,
    int N, int Kc)
{
  __shared__ _Float16 sAh[128 * 32];
  __shared__ _Float16 sBh[128 * 32];
  __shared__ _Float16 sAl[SPLIT == 3 ? 128 * 32 : 8];
  __shared__ _Float16 sBl[SPLIT == 3 ? 128 * 32 : 8];

  const int tid = threadIdx.x, lane = tid & 63, wid = tid >> 6;
  const int wm = wid >> 1, wn = wid & 1;
  const int l16 = lane & 15, k8 = lane >> 4;
  const int sr = lane >> 2;
  const int scol = ((lane & 3) ^ ((lane >> 3) & 3)) * 8;   // swizzled src col
  const int koff = ((k8 ^ ((lane >> 1) & 3))) * 8;         // swizzled read off

  const int  kt0   = blockIdx.z * Kc;
  const long abase = (long)(SWAPXY ? blockIdx.x : blockIdx.y) * 128;
  const long bbase = (long)(SWAPXY ? blockIdx.y : blockIdx.x) * 128;

  const int r0 = wid * 32 + sr;
  const int r1 = wid * 32 + 16 + sr;
  long br0 = bbase + r0, br1 = bbase + r1;
  if (NGUARD) {
    if (br0 > N - 1) br0 = N - 1;
    if (br1 > N - 1) br1 = N - 1;
  }

  const _Float16* ga0 = Ahp + (abase + r0) * (long)lda + kt0 + scol;
  const _Float16* ga1 = Ahp + (abase + r1) * (long)lda + kt0 + scol;
  const _Float16* gb0 = Bhp + br0 * (long)ldb + kt0 + scol;
  const _Float16* gb1 = Bhp + br1 * (long)ldb + kt0 + scol;
  const _Float16* la0 = SPLIT == 3 ? Alp + (abase + r0) * (long)lda + kt0 + scol : nullptr;
  const _Float16* la1 = SPLIT == 3 ? Alp + (abase + r1) * (long)lda + kt0 + scol : nullptr;
  const _Float16* lb0 = SPLIT == 3 ? Blp + br0 * (long)ldb + kt0 + scol : nullptr;
  const _Float16* lb1 = SPLIT == 3 ? Blp + br1 * (long)ldb + kt0 + scol : nullptr;

  const int e0 = (wid * 32) * 32;
  const int e1 = (wid * 32 + 16) * 32;

  f32x4 acc[4][4];
#pragma unroll
  for (int i = 0; i < 4; i++)
#pragma unroll
    for (int j = 0; j < 4; j++) acc[i][j] = (f32x4){0.f, 0.f, 0.f, 0.f};

  for (int kk = 0; kk < Kc; kk += 32) {
    gl_lds16(ga0 + kk, sAh + e0);
    gl_lds16(ga1 + kk, sAh + e1);
    gl_lds16(gb0 + kk, sBh + e0);
    gl_lds16(gb1 + kk, sBh + e1);
    if (SPLIT == 3) {
      gl_lds16(la0 + kk, sAl + e0);
      gl_lds16(la1 + kk, sAl + e1);
      gl_lds16(lb0 + kk, sBl + e0);
      gl_lds16(lb1 + kk, sBl + e1);
    }
    __syncthreads();

    half8 ah[4], bh[4];
#pragma unroll
    for (int m = 0; m < 4; m++)
      ah[m] = *(const half8*)&sAh[(wm * 64 + m * 16 + l16) * 32 + koff];
#pragma unroll
    for (int n = 0; n < 4; n++)
      bh[n] = *(const half8*)&sBh[(wn * 64 + n * 16 + l16) * 32 + koff];
#pragma unroll
    for (int m = 0; m < 4; m++)
#pragma unroll
      for (int n = 0; n < 4; n++)
        acc[m][n] = __builtin_amdgcn_mfma_f32_16x16x32_f16(ah[m], bh[n], acc[m][n], 0, 0, 0);
    if (SPLIT == 3) {
      half8 al[4], bl[4];
#pragma unroll
      for (int m = 0; m < 4; m++)
        al[m] = *(const half8*)&sAl[(wm * 64 + m * 16 + l16) * 32 + koff];
#pragma unroll
      for (int n = 0; n < 4; n++)
        bl[n] = *(const half8*)&sBl[(wn * 64 + n * 16 + l16) * 32 + koff];
#pragma unroll
      for (int m = 0; m < 4; m++)
#pragma unroll
        for (int n = 0; n < 4; n++) {
          acc[m][n] = __builtin_amdgcn_mfma_f32_16x16x32_f16(al[m], bh[n], acc[m][n], 0, 0, 0);
          acc[m][n] = __builtin_amdgcn_mfma_f32_16x16x32_f16(ah[m], bl[n], acc[m][n], 0, 0, 0);
        }
    }
    __syncthreads();
  }

  const long czoff = (long)blockIdx.z * czstride;
#pragma unroll
  for (int m = 0; m < 4; m++)
#pragma unroll
    for (int n = 0; n < 4; n++) {
      const long row0 = abase + wm * 64 + m * 16 + (lane >> 4) * 4;
      const long col  = bbase + wn * 64 + n * 16 + l16;
      if (!NGUARD || col < N) {
#pragma unroll
        for (int j = 0; j < 4; j++) {
          const long idx = (row0 + j) * (long)ldc + col + czoff;
          if (OUT16) ((_Float16*)Cp)[idx] = (_Float16)acc[m][n][j];
          else       ((float*)Cp)[idx] = acc[m][n][j];
        }
      }
    }
}

// ---------------------------------------------------------------------------
__global__ __launch_bounds__(256) void pack_kernel(
    const float* __restrict__ xt, const float* __restrict__ fc,
    const float* __restrict__ sh,
    _Float16* __restrict__ X1h, _Float16* __restrict__ X1l)
{
  int i = blockIdx.x * 256 + threadIdx.x;   // [0, 512*1024)
  int b = i >> 10, rr = i & 1023;
  long base = (long)b * 4096;
  float v[4];
  v[0] = sh[524288 + i];   // prev_h = state_h[1]
  v[1] = fc[i];
  v[2] = xt[i];
  v[3] = sh[i];            // state_h[0] (hidden)
#pragma unroll
  for (int j = 0; j < 4; j++) {
    _Float16 h = (_Float16)v[j];
    X1h[base + j * 1024 + rr] = h;
    X1l[base + j * 1024 + rr] = (_Float16)(v[j] - (float)h);
  }
}

__global__ __launch_bounds__(256) void convertA_kernel(
    const float* __restrict__ WihA, const float* __restrict__ WhhA,
    const float* __restrict__ Wh1, const float* __restrict__ Wh2,
    const float* __restrict__ Wvf, const float* __restrict__ Wpvf,
    _Float16* __restrict__ WcAh, _Float16* __restrict__ WcAl,
    _Float16* __restrict__ W12h, _Float16* __restrict__ Wvfh,
    _Float16* __restrict__ Wvfl, _Float16* __restrict__ Wpvfh)
{
  int bi = blockIdx.x, t = threadIdx.x;
  if (bi < 16384) {                       // Wc_att [4096][4096] hi+lo
    long e = ((long)bi * 256 + t) * 4;
    int row = (int)(e >> 12), col = (int)(e & 4095);
    const float* src = (col < 3072) ? WihA + (long)row * 3072 + col
                                    : WhhA + (long)row * 1024 + (col - 3072);
    f32x4 v = *(const f32x4*)src;
    half4 h, l;
#pragma unroll
    for (int j = 0; j < 4; j++) { h[j] = (_Float16)v[j]; l[j] = (_Float16)(v[j] - (float)h[j]); }
    *(half4*)&WcAh[e] = h;
    *(half4*)&WcAl[e] = l;
  } else if (bi < 17408) {                // Whh12 [1024][1024]
    long e = ((long)(bi - 16384) * 256 + t) * 4;
    int row = (int)(e >> 10), col = (int)(e & 1023);
    const float* src = (row < 512) ? Wh1 + (long)row * 1024 + col
                                   : Wh2 + (long)(row - 512) * 1024 + col;
    f32x4 v = *(const f32x4*)src;
    half4 h;
#pragma unroll
    for (int j = 0; j < 4; j++) h[j] = (_Float16)v[j];
    *(half4*)&W12h[e] = h;
  } else if (bi < 17800) {                // Wvf [196][2048] hi+lo
    long e = ((long)(bi - 17408) * 256 + t) * 4;
    f32x4 v = *(const f32x4*)(Wvf + e);
    half4 h, l;
#pragma unroll
    for (int j = 0; j < 4; j++) { h[j] = (_Float16)v[j]; l[j] = (_Float16)(v[j] - (float)h[j]); }
    *(half4*)&Wvfh[e] = h;
    *(half4*)&Wvfl[e] = l;
  } else {                                // Wpvf [512][1024]
    long e = ((long)(bi - 17800) * 256 + t) * 4;
    f32x4 v = *(const f32x4*)(Wpvf + e);
    half4 h;
#pragma unroll
    for (int j = 0; j < 4; j++) h[j] = (_Float16)v[j];
    *(half4*)&Wpvfh[e] = h;
  }
}

__global__ __launch_bounds__(256) void convertL_kernel(
    const float* __restrict__ WihL, const float* __restrict__ WhhL,
    _Float16* __restrict__ WcLh)
{
  long e = ((long)blockIdx.x * 256 + threadIdx.x) * 4;
  int row = (int)(e >> 12), col = (int)(e & 4095);
  const float* src = (col < 3072) ? WihL + (long)row * 3072 + col
                                  : WhhL + (long)row * 1024 + (col - 3072);
  f32x4 v = *(const f32x4*)src;
  half4 h;
#pragma unroll
  for (int j = 0; j < 4; j++) h[j] = (_Float16)v[j];
  *(half4*)&WcLh[e] = h;
}

// LSTM activation; sums NP K-split partials (f32 or fp16 per H16).
template<int NP, bool H16, bool ATT>
__global__ __launch_bounds__(256) void lstm_act_kernel(
    const void* __restrict__ gp, const float* __restrict__ bih,
    const float* __restrict__ bhh, const float* __restrict__ cin,
    float* __restrict__ hOut, float* __restrict__ cOut,
    _Float16* __restrict__ hatt_h, _Float16* __restrict__ conch,
    _Float16* __restrict__ concl, float* __restrict__ hOut2)
{
  const long S = 2097152;   // 512*4096
  int i = blockIdx.x * 256 + threadIdx.x;   // [0, 512*1024)
  int b = i >> 10, rr = i & 1023;
  long gb = (long)b * 4096;
  float g4[4];
#pragma unroll
  for (int q = 0; q < 4; q++) {
    float s = 0.f;
#pragma unroll
    for (int z = 0; z < NP; z++) {
      long off = (long)z * S + gb + q * 1024 + rr;
      s += H16 ? (float)((const _Float16*)gp)[off] : ((const float*)gp)[off];
    }
    g4[q] = s + bih[q * 1024 + rr] + bhh[q * 1024 + rr];
  }
  float c  = cin[i];
  float c2 = fast_sigmoid(g4[1]) * c + fast_sigmoid(g4[0]) * fast_tanh(g4[2]);
  float h2 = fast_sigmoid(g4[3]) * fast_tanh(c2);
  hOut[i] = h2;
  cOut[i] = c2;
  if (hOut2) hOut2[i] = h2;
  if (ATT) {
    _Float16 hh = (_Float16)h2;
    hatt_h[i] = hh;
    conch[(long)b * 2048 + 1024 + rr] = hh;
    concl[(long)b * 2048 + 1024 + rr] = (_Float16)(h2 - (float)hh);
  }
}

__global__ __launch_bounds__(256) void x2fill_kernel(
    const float* __restrict__ hatt, const float* __restrict__ sh,
    _Float16* __restrict__ x2h)
{
  int i = blockIdx.x * 256 + threadIdx.x;   // [0, 512*1024)
  int b = i >> 10, rr = i & 1023;
  x2h[(long)b * 4096 + 1024 + rr] = (_Float16)hatt[i];
  x2h[(long)b * 4096 + 3072 + rr] = (_Float16)sh[524288 + i];
}

__global__ __launch_bounds__(256) void reduce_atth_kernel(
    const float* __restrict__ p, float* __restrict__ o)
{
  int i = (blockIdx.x * 256 + threadIdx.x) * 4;   // 524288 elems, grid 512
  f32x4 a = *(const f32x4*)(p + i);
  f32x4 b = *(const f32x4*)(p + 524288 + i);
  f32x4 c = *(const f32x4*)(p + 1048576 + i);
  f32x4 d = *(const f32x4*)(p + 1572864 + i);
  *(f32x4*)(o + i) = a + b + c + d;
}

// attention-1 scores (one wave per (b,s) row)
__global__ __launch_bounds__(256) void score1_kernel(
    const float* __restrict__ pf, const float* __restrict__ atth,
    const float* __restrict__ bh,
    const float* __restrict__ walpha, const float* __restrict__ balpha,
    float* __restrict__ out, int nrows)
{
  int gw = blockIdx.x * 4 + (threadIdx.x >> 6);
  int lane = threadIdx.x & 63;
  if (gw >= nrows) return;
  int b = gw / 196;
  const float* p  = pf + (long)gw * 512 + lane * 8;
  const float* ah = atth + (long)b * 1024 + lane * 8;
  const float* bp = bh + lane * 8;
  const float* wp = walpha + lane * 8;
  float acc = 0.f;
#pragma unroll
  for (int u = 0; u < 2; u++) {
    f32x4 pv = *(const f32x4*)(p + u * 4);
    f32x4 av = *(const f32x4*)(ah + u * 4);
    f32x4 bv = *(const f32x4*)(bp + u * 4);
    f32x4 wv = *(const f32x4*)(wp + u * 4);
#pragma unroll
    for (int j = 0; j < 4; j++)
      acc += fast_tanh(pv[j] + av[j] + bv[j]) * wv[j];
  }
#pragma unroll
  for (int off = 32; off; off >>= 1) acc += __shfl_xor(acc, off);
  if (lane == 0) out[gw] = acc + balpha[0];
}

__global__ __launch_bounds__(256) void attsum1_kernel(
    const float* __restrict__ scores, const float* __restrict__ feats,
    _Float16* __restrict__ conch, _Float16* __restrict__ concl, _Float16* __restrict__ x2h)
{
  __shared__ float w[256];
  int b = blockIdx.x, t = threadIdx.x;
  float s0 = (t < 196) ? scores[b * 196 + t] : -3.0e38f;
  w[t] = s0;
  __syncthreads();
  float mx = -3.0e38f;
  for (int i = 0; i < 196; i++) mx = fmaxf(mx, w[i]);
  float sum = 0.f;
  for (int i = 0; i < 196; i++) sum += __expf(w[i] - mx);
  float inv = 1.f / sum;
  __syncthreads();
  if (t < 196) w[t] = __expf(s0 - mx) * inv;
  __syncthreads();
  f32x4 acc = (f32x4){0.f, 0.f, 0.f, 0.f};
  const float* fb = feats + (long)b * 200704 + t * 4;
  for (int s0i = 0; s0i < 192; s0i += 8) {
    f32x4 v[8];
#pragma unroll
    for (int u = 0; u < 8; u++) v[u] = *(const f32x4*)(fb + (long)(s0i + u) * 1024);
#pragma unroll
    for (int u = 0; u < 8; u++) {
      float ws = w[s0i + u];
#pragma unroll
      for (int j = 0; j < 4; j++) acc[j] += ws * v[u][j];
    }
  }
#pragma unroll
  for (int u = 192; u < 196; u++) {
    float ws = w[u];
    f32x4 v = *(const f32x4*)(fb + (long)u * 1024);
#pragma unroll
    for (int j = 0; j < 4; j++) acc[j] += ws * v[j];
  }
  half4 h, l;
#pragma unroll
  for (int j = 0; j < 4; j++) { h[j] = (_Float16)acc[j]; l[j] = (_Float16)(acc[j] - (float)h[j]); }
  *(half4*)&conch[(long)b * 2048 + t * 4] = h;
  *(half4*)&concl[(long)b * 2048 + t * 4] = l;
  *(half4*)&x2h[(long)b * 4096 + 2048 + t * 4] = h;
}

// merged attention-2: scores (tanh-dot over pvf16) + softmax + weighted sum
__global__ __launch_bounds__(256) void vfatt_kernel(
    const _Float16* __restrict__ pvf16, const float* __restrict__ atth2,
    const float* __restrict__ bh2att2, const float* __restrict__ b_pvf,
    const float* __restrict__ walpha2, const float* __restrict__ balpha2,
    const _Float16* __restrict__ arr1h, _Float16* __restrict__ x2h)
{
  __shared__ float w[40];
  int b = blockIdx.x, tid = threadIdx.x;
  int lane = tid & 63, wv = tid >> 6;

  float add[8], wal[8];
#pragma unroll
  for (int u = 0; u < 8; u++) {
    int a = lane * 8 + u;
    add[u] = atth2[(long)b * 1024 + a] + bh2att2[a] + b_pvf[a];
    wal[u] = walpha2[a];
  }
  for (int j = wv; j < 36; j += 4) {
    half8 hv = *(const half8*)&pvf16[((long)b * 36 + j) * 512 + lane * 8];
    float acc = 0.f;
#pragma unroll
    for (int u = 0; u < 8; u++)
      acc += fast_tanh((float)hv[u] + add[u]) * wal[u];
#pragma unroll
    for (int off = 32; off; off >>= 1) acc += __shfl_xor(acc, off);
    if (lane == 0) w[j] = acc + balpha2[0];
  }
  __syncthreads();
  float mx = -3.0e38f;
  for (int i = 0; i < 36; i++) mx = fmaxf(mx, w[i]);
  float sum = 0.f;
  for (int i = 0; i < 36; i++) sum += __expf(w[i] - mx);
  float inv = 1.f / sum;
  __syncthreads();
  if (tid < 36) w[tid] = __expf(w[tid] - mx) * inv;
  __syncthreads();
  f32x4 acc = (f32x4){0.f, 0.f, 0.f, 0.f};
  const _Float16* fb = arr1h + (long)b * 36 * 1024 + tid * 4;
#pragma unroll 4
  for (int s = 0; s < 36; s++) {
    float ws = w[s];
    half4 v = *(const half4*)(fb + (long)s * 1024);
#pragma unroll
    for (int j = 0; j < 4; j++) acc[j] += ws * (float)v[j];
  }
  half4 h;
#pragma unroll
  for (int j = 0; j < 4; j++) h[j] = (_Float16)acc[j];
  *(half4*)&x2h[(long)b * 4096 + tid * 4] = h;
}

// one wave per b: top-36 of (sum_z vfhap[z,b,s]) + b_vf[s]  (index set only)
template<int NP>
__global__ __launch_bounds__(64) void topk_kernel(
    const float* __restrict__ vfp, const float* __restrict__ b_vf, int* __restrict__ ix)
{
  int b = blockIdx.x;
  int lane = threadIdx.x;
  float v[4];
#pragma unroll
  for (int j = 0; j < 4; j++) {
    int s = lane + 64 * j;
    float sum = -3.0e38f;
    if (s < 196) {
      sum = b_vf[s];
#pragma unroll
      for (int z = 0; z < NP; z++) sum += vfp[(long)z * 100352 + b * 196 + s];
    }
    v[j] = sum;
  }
  for (int it = 0; it < 36; it++) {
    float bv = -3.0e38f; int bs = 1 << 20;
#pragma unroll
    for (int j = 0; j < 4; j++) {
      int s = lane + 64 * j;
      if (v[j] > bv) { bv = v[j]; bs = s; }
    }
#pragma unroll
    for (int off = 32; off; off >>= 1) {
      float ov = __shfl_xor(bv, off);
      int   os = __shfl_xor(bs, off);
      if (ov > bv || (ov == bv && os < bs)) { bv = ov; bs = os; }
    }
    if ((bs & 63) == lane) v[bs >> 6] = -3.0e38f;
    if (lane == 0) ix[b * 36 + it] = bs;
  }
}

__global__ __launch_bounds__(256) void gather_conv_kernel(
    const float* __restrict__ feats, const int* __restrict__ ix, _Float16* __restrict__ dst)
{
  int bj = blockIdx.x;
  int b = bj / 36;
  int s = ix[bj];
  int t = threadIdx.x;
  f32x4 v = *(const f32x4*)(feats + ((long)b * 196 + s) * 1024 + t * 4);
  half4 h;
#pragma unroll
  for (int j = 0; j < 4; j++) h[j] = (_Float16)v[j];
  *(half4*)&dst[(long)bj * 1024 + t * 4] = h;
}

// ---------------------------------------------------------------------------
extern "C" void kernel_launch(void* const* d_in, const int* in_sizes, int n_in,
                              void* d_out, int out_size, void* d_ws, size_t ws_size,
                              hipStream_t stream) {
  const float* xt        = (const float*)d_in[0];
  const float* fc_feats  = (const float*)d_in[1];
  const float* att_feats = (const float*)d_in[2];
  const float* p_att     = (const float*)d_in[3];
  const float* state_h   = (const float*)d_in[4];
  const float* state_c   = (const float*)d_in[5];
  const float* b_ih_att  = (const float*)d_in[7];
  const float* b_hh_att  = (const float*)d_in[9];
  const float* b_ih_lang = (const float*)d_in[11];
  const float* b_hh_lang = (const float*)d_in[13];
  const float* bh2att1   = (const float*)d_in[15];
  const float* Walpha1   = (const float*)d_in[16];
  const float* balpha1   = (const float*)d_in[17];
  const float* bh2att2   = (const float*)d_in[19];
  const float* Walpha2   = (const float*)d_in[20];
  const float* balpha2   = (const float*)d_in[21];
  const float* b_vf      = (const float*)d_in[23];
  const float* b_pvf     = (const float*)d_in[25];

  float* out = (float*)d_out;
  float* W = (float*)d_ws;   // pool, f32-unit offsets

  // --- static regions ---
  _Float16* WcAh   = (_Float16*)(W + 0);         // [4096][4096] hi; later WcLh
  _Float16* WcAl   = (_Float16*)(W + 8388608);   // [4096][4096] lo
  _Float16* X1h    = (_Float16*)(W + 16777216);  // [512][4096]
  _Float16* X1l    = (_Float16*)(W + 17825792);  // [512][4096]
  float*    g1p    = W + 18874368;               // [4][512][4096] f32 (z=4)
  _Float16* hatt_h = (_Float16*)(W + 27262976);  // [512][1024]
  _Float16* W12h   = (_Float16*)(W + 27525120);  // [1024][1024]
  _Float16* Wvfh   = (_Float16*)(W + 28049408);  // [196][2048]
  _Float16* Wvfl   = (_Float16*)(W + 28250112);  // [196][2048]
  _Float16* Wpvfh  = (_Float16*)(W + 28450816);  // [512][1024]  (high water 114.9MB)
  // --- overlays ---
  _Float16* WcLh   = WcAh;                        // lang weights, after att gemm
  float*    vfhap  = W + 8388608;                 // [16][512][196] f32 (over dead WcAl)
  _Float16* arr1h  = (_Float16*)(W + 8388608);    // [18432][1024] fp16, after topk
  _Float16* g2ph   = (_Float16*)(W + 8388608);    // [4][512][4096] fp16, after vfatt
  _Float16* conch  = (_Float16*)(W + 17825792);   // [512][2048] (over dead X1l)
  _Float16* concl  = (_Float16*)(W + 18350080);   // [512][2048]
  int*      vfix   = (int*)(W + 17825792);        // [512*36], after vfha gemm read conc
  float*    atthp  = W + 18874368;                // [4][512][1024] (inside dead g1p)
  float*    atth   = W + 20971520;                // [512][1024]
  _Float16* X2h    = (_Float16*)(W + 21495808);   // [512][4096]
  float*    scores1= W + 22544384;                // [512*196]
  _Float16* pvf16  = (_Float16*)(W + 22544384);   // [18432][512] fp16, after attsum1

  float* out_h0 = out + 524288;
  float* out_h1 = out + 2 * 524288;
  float* out_c0 = out + 3 * 524288;
  float* out_c1 = out + 4 * 524288;

  // 1. pack X1 hi/lo
  pack_kernel<<<2048, 256, 0, stream>>>(xt, fc_feats, state_h, X1h, X1l);

  // 2. convert weights (all but lang)
  convertA_kernel<<<18312, 256, 0, stream>>>(
      (const float*)d_in[6], (const float*)d_in[8],
      (const float*)d_in[14], (const float*)d_in[18],
      (const float*)d_in[22], (const float*)d_in[24],
      WcAh, WcAl, W12h, Wvfh, Wvfl, Wpvfh);

  // 3. att-LSTM gates: TM=512 (W read once), split-3, z=4, dbuf pipeline
  gemm_big<3, 0><<<dim3(4, 64), 512, 0, stream>>>(
      X1h, X1l, WcAh, WcAl, 4096, 1024, g1p, 2097152);

  // 4. convert lang weights (over dead WcAh)
  convertL_kernel<<<16384, 256, 0, stream>>>(
      (const float*)d_in[10], (const float*)d_in[12], WcLh);

  // 5. att-LSTM activation (sums 4 f32 partials)
  lstm_act_kernel<4, false, true><<<2048, 256, 0, stream>>>(
      g1p, b_ih_att, b_hh_att, state_c, out_h0, out_c0,
      hatt_h, conch, concl, nullptr);

  // 6. X2h slots 1024/3072
  x2fill_kernel<<<2048, 256, 0, stream>>>(out_h0, state_h, X2h);

  // 7. fused atth1|atth2 projection, z=4
  gemm16<1, 0, 0, 0><<<dim3(8, 4, 4), 256, 0, stream>>>(
      hatt_h, nullptr, 1024, W12h, nullptr, 1024, atthp, 1024, 524288, 1024, 256);
  reduce_atth_kernel<<<512, 256, 0, stream>>>(atthp, atth);

  // 8. attention-1 scores
  score1_kernel<<<25088, 256, 0, stream>>>(
      p_att, atth, bh2att1, Walpha1, balpha1, scores1, 100352);

  // 9. attention-1 softmax + weighted sum
  attsum1_kernel<<<512, 256, 0, stream>>>(scores1, att_feats, conch, concl, X2h);

  // 10. vf logits, split-3, z=16 (128 blocks; partials summed in topk)
  gemm16<3, 0, 1, 0><<<dim3(2, 4, 16), 256, 0, stream>>>(
      conch, concl, 2048, Wvfh, Wvfl, 2048, vfhap, 196, 100352, 196, 128);

  // 11. top-36
  topk_kernel<16><<<512, 64, 0, stream>>>(vfhap, b_vf, vfix);

  // 12. gather + fp16 convert
  gather_conv_kernel<<<18432, 256, 0, stream>>>(att_feats, vfix, arr1h);

  // 13. p_vf_feats (fp16 out); SWAPXY grid: same-M blocks stride 144 (=0 mod 8)
  gemm16<1, 1, 0, 1><<<dim3(144, 4, 1), 256, 0, stream>>>(
      arr1h, nullptr, 1024, Wpvfh, nullptr, 1024, pvf16, 512, 0, 512, 1024);

  // 14. attention-2 merged: scores + softmax + weighted sum -> X2h[:,0:1024]
  vfatt_kernel<<<512, 256, 0, stream>>>(
      pvf16, atth + 512, bh2att2, b_pvf, Walpha2, balpha2, arr1h, X2h);

  // 15. lang-LSTM gates: TM=512, plain fp16, z=4, fp16 partials
  gemm_big<1, 1><<<dim3(4, 64), 512, 0, stream>>>(
      X2h, nullptr, WcLh, nullptr, 4096, 1024, g2ph, 2097152);

  // 16. lang-LSTM activation -> output (sums 4 fp16 partials)
  lstm_act_kernel<4, true, false><<<2048, 256, 0, stream>>>(
      g2ph, b_ih_lang, b_hh_lang, state_c + 524288, out, out_c1,
      nullptr, nullptr, nullptr, out_h1);
}

// Round 5
// 411.908 us; speedup vs baseline: 1.1323x; 1.1323x over previous
//
#include <hip/hip_runtime.h>

typedef __attribute__((ext_vector_type(4))) float f32x4;
typedef __attribute__((ext_vector_type(8))) _Float16 half8;
typedef __attribute__((ext_vector_type(4))) _Float16 half4;

__device__ __forceinline__ float fast_tanh(float x) {
  float e = __expf(2.f * x);
  return 1.f - 2.f / (e + 1.f);
}
__device__ __forceinline__ float fast_sigmoid(float x) {
  return 1.f / (1.f + __expf(-x));
}

__device__ __forceinline__ void gl_lds16(const _Float16* g, _Float16* l) {
  __builtin_amdgcn_global_load_lds(
      (const __attribute__((address_space(1))) void*)g,
      (__attribute__((address_space(3))) void*)l, 16, 0, 0);
}

// ---------------------------------------------------------------------------
// C[M,N] = A[M,K] @ B[N,K]^T, fp16 (hi/lo split-3 optional), f32 accum.
// 128x128 tile, 4 waves, BK=32, DOUBLE-buffered LDS with counted-vmcnt
// pipeline (T3/T4 minimum): STAGE(t+1) issued before compute(t); raw
// s_barrier + s_waitcnt vmcnt(Ns) keeps prev-step loads retiring under MFMA.
// Two raw barriers per step (2nd = WAR guard for the 2-buffer cycle).
// blockIdx: x = N-tile (fastest), y = M-tile, z = K-split (SWAPXY swaps x/y).
// ---------------------------------------------------------------------------
template<int SPLIT, int OUT16, int NGUARD, int SWAPXY>
__global__ __launch_bounds__(256) void gemm16(
    const _Float16* __restrict__ Ahp, const _Float16* __restrict__ Alp, int lda,
    const _Float16* __restrict__ Bhp, const _Float16* __restrict__ Blp, int ldb,
    void* __restrict__ Cp, int ldc, long czstride,
    int N, int Kc)
{
  __shared__ _Float16 sAh[2][128 * 32];
  __shared__ _Float16 sBh[2][128 * 32];
  __shared__ _Float16 sAl[SPLIT == 3 ? 2 : 1][SPLIT == 3 ? 128 * 32 : 8];
  __shared__ _Float16 sBl[SPLIT == 3 ? 2 : 1][SPLIT == 3 ? 128 * 32 : 8];

  const int tid = threadIdx.x, lane = tid & 63, wid = tid >> 6;
  const int wm = wid >> 1, wn = wid & 1;
  const int l16 = lane & 15, k8 = lane >> 4;
  const int sr = lane >> 2;
  const int scol = ((lane & 3) ^ ((lane >> 3) & 3)) * 8;   // swizzled src col
  const int koff = ((k8 ^ ((lane >> 1) & 3))) * 8;         // swizzled read off

  const int  kt0   = blockIdx.z * Kc;
  const long abase = (long)(SWAPXY ? blockIdx.x : blockIdx.y) * 128;
  const long bbase = (long)(SWAPXY ? blockIdx.y : blockIdx.x) * 128;

  const int r0 = wid * 32 + sr;
  const int r1 = wid * 32 + 16 + sr;
  long br0 = bbase + r0, br1 = bbase + r1;
  if (NGUARD) {
    if (br0 > N - 1) br0 = N - 1;
    if (br1 > N - 1) br1 = N - 1;
  }

  const _Float16* ga0 = Ahp + (abase + r0) * (long)lda + kt0 + scol;
  const _Float16* ga1 = Ahp + (abase + r1) * (long)lda + kt0 + scol;
  const _Float16* gb0 = Bhp + br0 * (long)ldb + kt0 + scol;
  const _Float16* gb1 = Bhp + br1 * (long)ldb + kt0 + scol;
  const _Float16* la0 = SPLIT == 3 ? Alp + (abase + r0) * (long)lda + kt0 + scol : nullptr;
  const _Float16* la1 = SPLIT == 3 ? Alp + (abase + r1) * (long)lda + kt0 + scol : nullptr;
  const _Float16* lb0 = SPLIT == 3 ? Blp + br0 * (long)ldb + kt0 + scol : nullptr;
  const _Float16* lb1 = SPLIT == 3 ? Blp + br1 * (long)ldb + kt0 + scol : nullptr;

  const int e0 = (wid * 32) * 32;        // wave-uniform LDS elem base, chunk 0
  const int e1 = (wid * 32 + 16) * 32;   // chunk 1

  f32x4 acc[4][4];
#pragma unroll
  for (int i = 0; i < 4; i++)
#pragma unroll
    for (int j = 0; j < 4; j++) acc[i][j] = (f32x4){0.f, 0.f, 0.f, 0.f};

  auto STAGE = [&](int buf, int kk) {
    gl_lds16(ga0 + kk, &sAh[buf][e0]);
    gl_lds16(ga1 + kk, &sAh[buf][e1]);
    gl_lds16(gb0 + kk, &sBh[buf][e0]);
    gl_lds16(gb1 + kk, &sBh[buf][e1]);
    if (SPLIT == 3) {
      gl_lds16(la0 + kk, &sAl[buf][e0]);
      gl_lds16(la1 + kk, &sAl[buf][e1]);
      gl_lds16(lb0 + kk, &sBl[buf][e0]);
      gl_lds16(lb1 + kk, &sBl[buf][e1]);
    }
  };

  STAGE(0, 0);

  const int nst = Kc >> 5;
  for (int t = 0; t < nst; t++) {
    const int buf = t & 1;
    if (t + 1 < nst) {
      STAGE(buf ^ 1, (t + 1) * 32);
      // wait only for PREV step's loads (Ns just issued stay in flight)
      if (SPLIT == 3) asm volatile("s_waitcnt vmcnt(8)" ::: "memory");
      else            asm volatile("s_waitcnt vmcnt(4)" ::: "memory");
    } else {
      asm volatile("s_waitcnt vmcnt(0)" ::: "memory");
    }
    __builtin_amdgcn_sched_barrier(0);
    __builtin_amdgcn_s_barrier();          // all waves' buf loads visible
    __builtin_amdgcn_sched_barrier(0);

    half8 ah[4], bh[4];
#pragma unroll
    for (int m = 0; m < 4; m++)
      ah[m] = *(const half8*)&sAh[buf][(wm * 64 + m * 16 + l16) * 32 + koff];
#pragma unroll
    for (int n = 0; n < 4; n++)
      bh[n] = *(const half8*)&sBh[buf][(wn * 64 + n * 16 + l16) * 32 + koff];
#pragma unroll
    for (int m = 0; m < 4; m++)
#pragma unroll
      for (int n = 0; n < 4; n++)
        acc[m][n] = __builtin_amdgcn_mfma_f32_16x16x32_f16(ah[m], bh[n], acc[m][n], 0, 0, 0);
    if (SPLIT == 3) {
      half8 al[4], bl[4];
#pragma unroll
      for (int m = 0; m < 4; m++)
        al[m] = *(const half8*)&sAl[buf][(wm * 64 + m * 16 + l16) * 32 + koff];
#pragma unroll
      for (int n = 0; n < 4; n++)
        bl[n] = *(const half8*)&sBl[buf][(wn * 64 + n * 16 + l16) * 32 + koff];
#pragma unroll
      for (int m = 0; m < 4; m++)
#pragma unroll
        for (int n = 0; n < 4; n++) {
          acc[m][n] = __builtin_amdgcn_mfma_f32_16x16x32_f16(al[m], bh[n], acc[m][n], 0, 0, 0);
          acc[m][n] = __builtin_amdgcn_mfma_f32_16x16x32_f16(ah[m], bl[n], acc[m][n], 0, 0, 0);
        }
    }
    __builtin_amdgcn_sched_barrier(0);
    __builtin_amdgcn_s_barrier();          // WAR guard: reads of buf done
    __builtin_amdgcn_sched_barrier(0);
  }

  const long czoff = (long)blockIdx.z * czstride;
#pragma unroll
  for (int m = 0; m < 4; m++)
#pragma unroll
    for (int n = 0; n < 4; n++) {
      const long row0 = abase + wm * 64 + m * 16 + (lane >> 4) * 4;
      const long col  = bbase + wn * 64 + n * 16 + l16;
      if (!NGUARD || col < N) {
#pragma unroll
        for (int j = 0; j < 4; j++) {
          const long idx = (row0 + j) * (long)ldc + col + czoff;
          if (OUT16) ((_Float16*)Cp)[idx] = (_Float16)acc[m][n][j];
          else       ((float*)Cp)[idx] = acc[m][n][j];
        }
      }
    }
}

// ---------------------------------------------------------------------------
__global__ __launch_bounds__(256) void pack_kernel(
    const float* __restrict__ xt, const float* __restrict__ fc,
    const float* __restrict__ sh,
    _Float16* __restrict__ X1h, _Float16* __restrict__ X1l)
{
  int i = blockIdx.x * 256 + threadIdx.x;   // [0, 512*1024)
  int b = i >> 10, rr = i & 1023;
  long base = (long)b * 4096;
  float v[4];
  v[0] = sh[524288 + i];   // prev_h = state_h[1]
  v[1] = fc[i];
  v[2] = xt[i];
  v[3] = sh[i];            // state_h[0] (hidden)
#pragma unroll
  for (int j = 0; j < 4; j++) {
    _Float16 h = (_Float16)v[j];
    X1h[base + j * 1024 + rr] = h;
    X1l[base + j * 1024 + rr] = (_Float16)(v[j] - (float)h);
  }
}

__global__ __launch_bounds__(256) void convertA_kernel(
    const float* __restrict__ WihA, const float* __restrict__ WhhA,
    const float* __restrict__ Wh1, const float* __restrict__ Wh2,
    const float* __restrict__ Wvf, const float* __restrict__ Wpvf,
    _Float16* __restrict__ WcAh, _Float16* __restrict__ WcAl,
    _Float16* __restrict__ W12h, _Float16* __restrict__ Wvfh,
    _Float16* __restrict__ Wvfl, _Float16* __restrict__ Wpvfh)
{
  int bi = blockIdx.x, t = threadIdx.x;
  if (bi < 16384) {                       // Wc_att [4096][4096] hi+lo
    long e = ((long)bi * 256 + t) * 4;
    int row = (int)(e >> 12), col = (int)(e & 4095);
    const float* src = (col < 3072) ? WihA + (long)row * 3072 + col
                                    : WhhA + (long)row * 1024 + (col - 3072);
    f32x4 v = *(const f32x4*)src;
    half4 h, l;
#pragma unroll
    for (int j = 0; j < 4; j++) { h[j] = (_Float16)v[j]; l[j] = (_Float16)(v[j] - (float)h[j]); }
    *(half4*)&WcAh[e] = h;
    *(half4*)&WcAl[e] = l;
  } else if (bi < 17408) {                // Whh12 [1024][1024]
    long e = ((long)(bi - 16384) * 256 + t) * 4;
    int row = (int)(e >> 10), col = (int)(e & 1023);
    const float* src = (row < 512) ? Wh1 + (long)row * 1024 + col
                                   : Wh2 + (long)(row - 512) * 1024 + col;
    f32x4 v = *(const f32x4*)src;
    half4 h;
#pragma unroll
    for (int j = 0; j < 4; j++) h[j] = (_Float16)v[j];
    *(half4*)&W12h[e] = h;
  } else if (bi < 17800) {                // Wvf [196][2048] hi+lo
    long e = ((long)(bi - 17408) * 256 + t) * 4;
    f32x4 v = *(const f32x4*)(Wvf + e);
    half4 h, l;
#pragma unroll
    for (int j = 0; j < 4; j++) { h[j] = (_Float16)v[j]; l[j] = (_Float16)(v[j] - (float)h[j]); }
    *(half4*)&Wvfh[e] = h;
    *(half4*)&Wvfl[e] = l;
  } else {                                // Wpvf [512][1024]
    long e = ((long)(bi - 17800) * 256 + t) * 4;
    f32x4 v = *(const f32x4*)(Wpvf + e);
    half4 h;
#pragma unroll
    for (int j = 0; j < 4; j++) h[j] = (_Float16)v[j];
    *(half4*)&Wpvfh[e] = h;
  }
}

__global__ __launch_bounds__(256) void convertL_kernel(
    const float* __restrict__ WihL, const float* __restrict__ WhhL,
    _Float16* __restrict__ WcLh)
{
  long e = ((long)blockIdx.x * 256 + threadIdx.x) * 4;
  int row = (int)(e >> 12), col = (int)(e & 4095);
  const float* src = (col < 3072) ? WihL + (long)row * 3072 + col
                                  : WhhL + (long)row * 1024 + (col - 3072);
  f32x4 v = *(const f32x4*)src;
  half4 h;
#pragma unroll
  for (int j = 0; j < 4; j++) h[j] = (_Float16)v[j];
  *(half4*)&WcLh[e] = h;
}

// LSTM activation; sums NP K-split partials (f32 or fp16 per H16).
// ATT variant also fills hatt_h, conc hi/lo slot, and X2h slots 1024/3072.
template<int NP, bool H16, bool ATT>
__global__ __launch_bounds__(256) void lstm_act_kernel(
    const void* __restrict__ gp, const float* __restrict__ bih,
    const float* __restrict__ bhh, const float* __restrict__ cin,
    float* __restrict__ hOut, float* __restrict__ cOut,
    _Float16* __restrict__ hatt_h, _Float16* __restrict__ conch,
    _Float16* __restrict__ concl, _Float16* __restrict__ x2h,
    const float* __restrict__ sh, float* __restrict__ hOut2)
{
  const long S = 2097152;   // 512*4096
  int i = blockIdx.x * 256 + threadIdx.x;   // [0, 512*1024)
  int b = i >> 10, rr = i & 1023;
  long gb = (long)b * 4096;
  float g4[4];
#pragma unroll
  for (int q = 0; q < 4; q++) {
    float s = 0.f;
#pragma unroll
    for (int z = 0; z < NP; z++) {
      long off = (long)z * S + gb + q * 1024 + rr;
      s += H16 ? (float)((const _Float16*)gp)[off] : ((const float*)gp)[off];
    }
    g4[q] = s + bih[q * 1024 + rr] + bhh[q * 1024 + rr];
  }
  float c  = cin[i];
  float c2 = fast_sigmoid(g4[1]) * c + fast_sigmoid(g4[0]) * fast_tanh(g4[2]);
  float h2 = fast_sigmoid(g4[3]) * fast_tanh(c2);
  hOut[i] = h2;
  cOut[i] = c2;
  if (hOut2) hOut2[i] = h2;
  if (ATT) {
    _Float16 hh = (_Float16)h2;
    hatt_h[i] = hh;
    conch[(long)b * 2048 + 1024 + rr] = hh;
    concl[(long)b * 2048 + 1024 + rr] = (_Float16)(h2 - (float)hh);
    x2h[(long)b * 4096 + 1024 + rr] = hh;
    x2h[(long)b * 4096 + 3072 + rr] = (_Float16)sh[524288 + i];
  }
}

__global__ __launch_bounds__(256) void reduce_atth_kernel(
    const float* __restrict__ p, float* __restrict__ o)
{
  int i = (blockIdx.x * 256 + threadIdx.x) * 4;   // 524288 elems, grid 512
  f32x4 a = *(const f32x4*)(p + i);
  f32x4 b = *(const f32x4*)(p + 524288 + i);
  f32x4 c = *(const f32x4*)(p + 1048576 + i);
  f32x4 d = *(const f32x4*)(p + 1572864 + i);
  *(f32x4*)(o + i) = a + b + c + d;
}

// attention-1 scores (one wave per (b,s) row)
__global__ __launch_bounds__(256) void score1_kernel(
    const float* __restrict__ pf, const float* __restrict__ atth,
    const float* __restrict__ bh,
    const float* __restrict__ walpha, const float* __restrict__ balpha,
    float* __restrict__ out, int nrows)
{
  int gw = blockIdx.x * 4 + (threadIdx.x >> 6);
  int lane = threadIdx.x & 63;
  if (gw >= nrows) return;
  int b = gw / 196;
  const float* p  = pf + (long)gw * 512 + lane * 8;
  const float* ah = atth + (long)b * 1024 + lane * 8;
  const float* bp = bh + lane * 8;
  const float* wp = walpha + lane * 8;
  float acc = 0.f;
#pragma unroll
  for (int u = 0; u < 2; u++) {
    f32x4 pv = *(const f32x4*)(p + u * 4);
    f32x4 av = *(const f32x4*)(ah + u * 4);
    f32x4 bv = *(const f32x4*)(bp + u * 4);
    f32x4 wv = *(const f32x4*)(wp + u * 4);
#pragma unroll
    for (int j = 0; j < 4; j++)
      acc += fast_tanh(pv[j] + av[j] + bv[j]) * wv[j];
  }
#pragma unroll
  for (int off = 32; off; off >>= 1) acc += __shfl_xor(acc, off);
  if (lane == 0) out[gw] = acc + balpha[0];
}

__global__ __launch_bounds__(256) void attsum1_kernel(
    const float* __restrict__ scores, const float* __restrict__ feats,
    _Float16* __restrict__ conch, _Float16* __restrict__ concl, _Float16* __restrict__ x2h)
{
  __shared__ float w[256];
  int b = blockIdx.x, t = threadIdx.x;
  float s0 = (t < 196) ? scores[b * 196 + t] : -3.0e38f;
  w[t] = s0;
  __syncthreads();
  float mx = -3.0e38f;
  for (int i = 0; i < 196; i++) mx = fmaxf(mx, w[i]);
  float sum = 0.f;
  for (int i = 0; i < 196; i++) sum += __expf(w[i] - mx);
  float inv = 1.f / sum;
  __syncthreads();
  if (t < 196) w[t] = __expf(s0 - mx) * inv;
  __syncthreads();
  f32x4 acc = (f32x4){0.f, 0.f, 0.f, 0.f};
  const float* fb = feats + (long)b * 200704 + t * 4;
  for (int s0i = 0; s0i < 192; s0i += 8) {
    f32x4 v[8];
#pragma unroll
    for (int u = 0; u < 8; u++) v[u] = *(const f32x4*)(fb + (long)(s0i + u) * 1024);
#pragma unroll
    for (int u = 0; u < 8; u++) {
      float ws = w[s0i + u];
#pragma unroll
      for (int j = 0; j < 4; j++) acc[j] += ws * v[u][j];
    }
  }
#pragma unroll
  for (int u = 192; u < 196; u++) {
    float ws = w[u];
    f32x4 v = *(const f32x4*)(fb + (long)u * 1024);
#pragma unroll
    for (int j = 0; j < 4; j++) acc[j] += ws * v[j];
  }
  half4 h, l;
#pragma unroll
  for (int j = 0; j < 4; j++) { h[j] = (_Float16)acc[j]; l[j] = (_Float16)(acc[j] - (float)h[j]); }
  *(half4*)&conch[(long)b * 2048 + t * 4] = h;
  *(half4*)&concl[(long)b * 2048 + t * 4] = l;
  *(half4*)&x2h[(long)b * 4096 + 2048 + t * 4] = h;
}

// merged attention-2: scores (tanh-dot over pvf16) + softmax + weighted sum
__global__ __launch_bounds__(256) void vfatt_kernel(
    const _Float16* __restrict__ pvf16, const float* __restrict__ atth2,
    const float* __restrict__ bh2att2, const float* __restrict__ b_pvf,
    const float* __restrict__ walpha2, const float* __restrict__ balpha2,
    const _Float16* __restrict__ arr1h, _Float16* __restrict__ x2h)
{
  __shared__ float w[40];
  int b = blockIdx.x, tid = threadIdx.x;
  int lane = tid & 63, wv = tid >> 6;

  float add[8], wal[8];
#pragma unroll
  for (int u = 0; u < 8; u++) {
    int a = lane * 8 + u;
    add[u] = atth2[(long)b * 1024 + a] + bh2att2[a] + b_pvf[a];
    wal[u] = walpha2[a];
  }
  for (int j = wv; j < 36; j += 4) {
    half8 hv = *(const half8*)&pvf16[((long)b * 36 + j) * 512 + lane * 8];
    float acc = 0.f;
#pragma unroll
    for (int u = 0; u < 8; u++)
      acc += fast_tanh((float)hv[u] + add[u]) * wal[u];
#pragma unroll
    for (int off = 32; off; off >>= 1) acc += __shfl_xor(acc, off);
    if (lane == 0) w[j] = acc + balpha2[0];
  }
  __syncthreads();
  float mx = -3.0e38f;
  for (int i = 0; i < 36; i++) mx = fmaxf(mx, w[i]);
  float sum = 0.f;
  for (int i = 0; i < 36; i++) sum += __expf(w[i] - mx);
  float inv = 1.f / sum;
  __syncthreads();
  if (tid < 36) w[tid] = __expf(w[tid] - mx) * inv;
  __syncthreads();
  f32x4 acc = (f32x4){0.f, 0.f, 0.f, 0.f};
  const _Float16* fb = arr1h + (long)b * 36 * 1024 + tid * 4;
#pragma unroll 4
  for (int s = 0; s < 36; s++) {
    float ws = w[s];
    half4 v = *(const half4*)(fb + (long)s * 1024);
#pragma unroll
    for (int j = 0; j < 4; j++) acc[j] += ws * (float)v[j];
  }
  half4 h;
#pragma unroll
  for (int j = 0; j < 4; j++) h[j] = (_Float16)acc[j];
  *(half4*)&x2h[(long)b * 4096 + tid * 4] = h;
}

// one wave per b: top-36 of (sum_z vfhap[z,b,s]) + b_vf[s]  (index set only)
template<int NP>
__global__ __launch_bounds__(64) void topk_kernel(
    const float* __restrict__ vfp, const float* __restrict__ b_vf, int* __restrict__ ix)
{
  int b = blockIdx.x;
  int lane = threadIdx.x;
  float v[4];
#pragma unroll
  for (int j = 0; j < 4; j++) {
    int s = lane + 64 * j;
    float sum = -3.0e38f;
    if (s < 196) {
      sum = b_vf[s];
#pragma unroll
      for (int z = 0; z < NP; z++) sum += vfp[(long)z * 100352 + b * 196 + s];
    }
    v[j] = sum;
  }
  for (int it = 0; it < 36; it++) {
    float bv = -3.0e38f; int bs = 1 << 20;
#pragma unroll
    for (int j = 0; j < 4; j++) {
      int s = lane + 64 * j;
      if (v[j] > bv) { bv = v[j]; bs = s; }
    }
#pragma unroll
    for (int off = 32; off; off >>= 1) {
      float ov = __shfl_xor(bv, off);
      int   os = __shfl_xor(bs, off);
      if (ov > bv || (ov == bv && os < bs)) { bv = ov; bs = os; }
    }
    if ((bs & 63) == lane) v[bs >> 6] = -3.0e38f;
    if (lane == 0) ix[b * 36 + it] = bs;
  }
}

__global__ __launch_bounds__(256) void gather_conv_kernel(
    const float* __restrict__ feats, const int* __restrict__ ix, _Float16* __restrict__ dst)
{
  int bj = blockIdx.x;
  int b = bj / 36;
  int s = ix[bj];
  int t = threadIdx.x;
  f32x4 v = *(const f32x4*)(feats + ((long)b * 196 + s) * 1024 + t * 4);
  half4 h;
#pragma unroll
  for (int j = 0; j < 4; j++) h[j] = (_Float16)v[j];
  *(half4*)&dst[(long)bj * 1024 + t * 4] = h;
}

// ---------------------------------------------------------------------------
extern "C" void kernel_launch(void* const* d_in, const int* in_sizes, int n_in,
                              void* d_out, int out_size, void* d_ws, size_t ws_size,
                              hipStream_t stream) {
  const float* xt        = (const float*)d_in[0];
  const float* fc_feats  = (const float*)d_in[1];
  const float* att_feats = (const float*)d_in[2];
  const float* p_att     = (const float*)d_in[3];
  const float* state_h   = (const float*)d_in[4];
  const float* state_c   = (const float*)d_in[5];
  const float* b_ih_att  = (const float*)d_in[7];
  const float* b_hh_att  = (const float*)d_in[9];
  const float* b_ih_lang = (const float*)d_in[11];
  const float* b_hh_lang = (const float*)d_in[13];
  const float* bh2att1   = (const float*)d_in[15];
  const float* Walpha1   = (const float*)d_in[16];
  const float* balpha1   = (const float*)d_in[17];
  const float* bh2att2   = (const float*)d_in[19];
  const float* Walpha2   = (const float*)d_in[20];
  const float* balpha2   = (const float*)d_in[21];
  const float* b_vf      = (const float*)d_in[23];
  const float* b_pvf     = (const float*)d_in[25];

  float* out = (float*)d_out;
  float* W = (float*)d_ws;   // pool, f32-unit offsets; ws_size ~1.6GB -> flat layout

  _Float16* WcAh   = (_Float16*)(W + 0);         // [4096][4096] fp16 hi
  _Float16* WcAl   = (_Float16*)(W + 8388608);   // [4096][4096] fp16 lo
  _Float16* WcLh   = (_Float16*)(W + 16777216);  // [4096][4096] fp16 (lang)
  _Float16* X1h    = (_Float16*)(W + 25165824);  // [512][4096]
  _Float16* X1l    = (_Float16*)(W + 26214400);  // [512][4096]
  float*    g1p    = W + 27262976;               // [4][512][4096] f32
  _Float16* hatt_h = (_Float16*)(W + 35651584);  // [512][1024]
  _Float16* W12h   = (_Float16*)(W + 35913728);  // [1024][1024]
  _Float16* Wvfh   = (_Float16*)(W + 36438016);  // [196][2048]
  _Float16* Wvfl   = (_Float16*)(W + 36638720);  // [196][2048]
  _Float16* Wpvfh  = (_Float16*)(W + 36839424);  // [512][1024]
  float*    atthp  = W + 37101568;               // [4][512][1024] f32
  float*    atth   = W + 39198720;               // [512][1024] f32
  _Float16* conch  = (_Float16*)(W + 39723008);  // [512][2048]
  _Float16* concl  = (_Float16*)(W + 40247296);  // [512][2048]
  _Float16* X2h    = (_Float16*)(W + 40771584);  // [512][4096]
  float*    scores1= W + 41820160;               // [512*196]
  float*    vfhap  = W + 41920512;               // [16][512][196] f32
  int*      vfix   = (int*)(W + 43526144);       // [512*36]
  _Float16* arr1h  = (_Float16*)(W + 43544576);  // [18432][1024]
  _Float16* pvf16  = (_Float16*)(W + 52981760);  // [18432][512]
  _Float16* g2ph   = (_Float16*)(W + 57700352);  // [4][512][4096] fp16
  // high water: 61894656 f32 = 247.6 MB << ws_size

  float* out_h0 = out + 524288;
  float* out_h1 = out + 2 * 524288;
  float* out_c0 = out + 3 * 524288;
  float* out_c1 = out + 4 * 524288;

  // 1. pack X1 hi/lo
  pack_kernel<<<2048, 256, 0, stream>>>(xt, fc_feats, state_h, X1h, X1l);

  // 2. convert weights (all but lang)
  convertA_kernel<<<18312, 256, 0, stream>>>(
      (const float*)d_in[6], (const float*)d_in[8],
      (const float*)d_in[14], (const float*)d_in[18],
      (const float*)d_in[22], (const float*)d_in[24],
      WcAh, WcAl, W12h, Wvfh, Wvfl, Wpvfh);

  // 3. att-LSTM gates: split-3, z=4 (512 blocks = 2/CU), counted-vmcnt pipeline
  gemm16<3, 0, 0, 0><<<dim3(32, 4, 4), 256, 0, stream>>>(
      X1h, X1l, 4096, WcAh, WcAl, 4096, g1p, 4096, 2097152, 4096, 1024);

  // 4. convert lang weights
  convertL_kernel<<<16384, 256, 0, stream>>>(
      (const float*)d_in[10], (const float*)d_in[12], WcLh);

  // 5. att-LSTM activation (sums 4 f32 partials; fills conc/X2h slots)
  lstm_act_kernel<4, false, true><<<2048, 256, 0, stream>>>(
      g1p, b_ih_att, b_hh_att, state_c, out_h0, out_c0,
      hatt_h, conch, concl, X2h, state_h, nullptr);

  // 6. fused atth1|atth2 projection, z=4 + reduce
  gemm16<1, 0, 0, 0><<<dim3(8, 4, 4), 256, 0, stream>>>(
      hatt_h, nullptr, 1024, W12h, nullptr, 1024, atthp, 1024, 524288, 1024, 256);
  reduce_atth_kernel<<<512, 256, 0, stream>>>(atthp, atth);

  // 7. attention-1 scores
  score1_kernel<<<25088, 256, 0, stream>>>(
      p_att, atth, bh2att1, Walpha1, balpha1, scores1, 100352);

  // 8. attention-1 softmax + weighted sum
  attsum1_kernel<<<512, 256, 0, stream>>>(scores1, att_feats, conch, concl, X2h);

  // 9. vf logits, split-3, z=16 (128 blocks; partials summed in topk)
  gemm16<3, 0, 1, 0><<<dim3(2, 4, 16), 256, 0, stream>>>(
      conch, concl, 2048, Wvfh, Wvfl, 2048, vfhap, 196, 100352, 196, 128);

  // 10. top-36
  topk_kernel<16><<<512, 64, 0, stream>>>(vfhap, b_vf, vfix);

  // 11. gather + fp16 convert
  gather_conv_kernel<<<18432, 256, 0, stream>>>(att_feats, vfix, arr1h);

  // 12. p_vf_feats (fp16 out); SWAPXY: same-M blocks stride 144 (=0 mod 8)
  gemm16<1, 1, 0, 1><<<dim3(144, 4, 1), 256, 0, stream>>>(
      arr1h, nullptr, 1024, Wpvfh, nullptr, 1024, pvf16, 512, 0, 512, 1024);

  // 13. attention-2 merged: scores + softmax + weighted sum -> X2h[:,0:1024]
  vfatt_kernel<<<512, 256, 0, stream>>>(
      pvf16, atth + 512, bh2att2, b_pvf, Walpha2, balpha2, arr1h, X2h);

  // 14. lang-LSTM gates: plain fp16, z=4, fp16 partials
  gemm16<1, 1, 0, 0><<<dim3(32, 4, 4), 256, 0, stream>>>(
      X2h, nullptr, 4096, WcLh, nullptr, 4096, g2ph, 4096, 2097152, 4096, 1024);

  // 15. lang-LSTM activation -> output (sums 4 fp16 partials)
  lstm_act_kernel<4, true, false><<<2048, 256, 0, stream>>>(
      g2ph, b_ih_lang, b_hh_lang, state_c + 524288, out, out_c1,
      nullptr, nullptr, nullptr, nullptr, nullptr, out_h1);
}